// Round 1
// baseline (966.166 us; speedup 1.0000x reference)
//
#include <hip/hip_runtime.h>
#include <hip/hip_bf16.h>
#include <stdint.h>

#define D 512
#define BATCH 256
#define SEQ 512
// M = BATCH*SEQ = 131072

typedef __attribute__((ext_vector_type(8))) short short8;
typedef __attribute__((ext_vector_type(4))) float floatx4;

__device__ __forceinline__ float bf2f(unsigned short u) {
    union { unsigned int i; float f; } x; x.i = ((unsigned int)u) << 16; return x.f;
}
__device__ __forceinline__ unsigned short f2bf(float f) {
    union { float f; unsigned int i; } x; x.f = f;
    unsigned int i = x.i;
    unsigned int lsb = (i >> 16) & 1u;
    i += 0x7fffu + lsb;
    return (unsigned short)(i >> 16);
}

__device__ __forceinline__ float wred_sum(float v) {
    #pragma unroll
    for (int o = 32; o; o >>= 1) v += __shfl_xor(v, o, 64);
    return v;
}
__device__ __forceinline__ float wred_max(float v) {
    #pragma unroll
    for (int o = 32; o; o >>= 1) v = fmaxf(v, __shfl_xor(v, o, 64));
    return v;
}

__device__ __forceinline__ void llds16(const void* g, void* l) {
    auto gp = (const __attribute__((address_space(1))) void*)(g);
    // AS(3) pointers are 32-bit; low 32 bits of a generic shared pointer are the LDS offset.
    auto lp = (__attribute__((address_space(3))) void*)(uintptr_t)(l);
    __builtin_amdgcn_global_load_lds(gp, lp, 16, 0, 0);
}

// ---------------- dist kernel: cos-sim + softmax (one block per batch) ----------------
// F32IN: read f32 state_emb and also write bf16 copy to s_bf_out.
template<bool F32IN>
__global__ __launch_bounds__(256)
void dist_kernel(const void* s_in_, const float* __restrict__ q,
                 float* __restrict__ dist_out, unsigned short* __restrict__ s_bf_out) {
    const int b = blockIdx.x;
    const int t = threadIdx.x;
    const int lane = t & 63, wv = t >> 6;

    __shared__ float qs[D];
    __shared__ float sc[SEQ];
    __shared__ float redbuf[8];
    __shared__ float qn_s, m_s, sum_s;

    float q0 = q[b * D + t], q1 = q[b * D + 256 + t];
    qs[t] = q0; qs[t + 256] = q1;
    float ss = wred_sum(q0 * q0 + q1 * q1);
    if (lane == 0) redbuf[wv] = ss;
    __syncthreads();
    if (t == 0) qn_s = sqrtf(redbuf[0] + redbuf[1] + redbuf[2] + redbuf[3]);
    __syncthreads();
    const float qn = qn_s;

    const size_t bbase = (size_t)b * (SEQ * D);
    for (int s = wv; s < SEQ; s += 4) {
        const size_t off = bbase + (size_t)s * D + lane * 8;
        float v[8];
        if (F32IN) {
            const float4* p = (const float4*)((const float*)s_in_ + off);
            float4 a = p[0], c = p[1];
            v[0] = a.x; v[1] = a.y; v[2] = a.z; v[3] = a.w;
            v[4] = c.x; v[5] = c.y; v[6] = c.z; v[7] = c.w;
            short8 w;
            #pragma unroll
            for (int j = 0; j < 8; ++j) w[j] = (short)f2bf(v[j]);
            *(short8*)(s_bf_out + off) = w;
        } else {
            short8 w = *(const short8*)((const unsigned short*)s_in_ + off);
            #pragma unroll
            for (int j = 0; j < 8; ++j) v[j] = bf2f((unsigned short)w[j]);
        }
        float dot = 0.f, nr = 0.f;
        #pragma unroll
        for (int j = 0; j < 8; ++j) {
            float qv = qs[lane * 8 + j];
            dot += v[j] * qv;
            nr += v[j] * v[j];
        }
        dot = wred_sum(dot);
        nr  = wred_sum(nr);
        if (lane == 0) {
            float sn = sqrtf(nr);
            sc[s] = 10.f * dot / fmaxf(qn * sn, 1e-8f);
        }
    }
    __syncthreads();

    // softmax over sc[0..511]
    float s0 = sc[t], s1 = sc[t + 256];
    float m = wred_max(fmaxf(s0, s1));
    if (lane == 0) redbuf[wv] = m;
    __syncthreads();
    if (t == 0) m_s = fmaxf(fmaxf(redbuf[0], redbuf[1]), fmaxf(redbuf[2], redbuf[3]));
    __syncthreads();
    const float mm = m_s;
    float e0 = __expf(s0 - mm), e1 = __expf(s1 - mm);
    float es = wred_sum(e0 + e1);
    if (lane == 0) redbuf[wv] = es;
    __syncthreads();
    if (t == 0) sum_s = redbuf[0] + redbuf[1] + redbuf[2] + redbuf[3];
    __syncthreads();
    const float inv = 1.f / sum_s;
    dist_out[b * SEQ + t] = e0 * inv;
    dist_out[b * SEQ + 256 + t] = e1 * inv;
}

// ---------------- GEMM: C = lrelu(A @ W^T + bias), bf16 in/out, fp32 accum ----------------
// A: [M, K=512] bf16 row-major.  Bt = W: [N=512, K=512] bf16 row-major (B-transposed input).
#define BM 128
#define BN 128
#define BK 32

__global__ __launch_bounds__(256)
void gemm_kernel(const unsigned short* __restrict__ A, const unsigned short* __restrict__ Bt,
                 const float* __restrict__ bias, unsigned short* __restrict__ C) {
    __shared__ __align__(16) unsigned short As[BM * BK];
    __shared__ __align__(16) unsigned short Bs[BN * BK];

    const int tileM = blockIdx.x * BM;
    const int tileN = blockIdx.y * BN;
    const int t = threadIdx.x, lane = t & 63, wv = t >> 6;
    const int wm = wv >> 1, wn = wv & 1;

    floatx4 acc[4][4];
    #pragma unroll
    for (int i = 0; i < 4; ++i)
        #pragma unroll
        for (int j = 0; j < 4; ++j) acc[i][j] = {0.f, 0.f, 0.f, 0.f};

    const int kg = (lane >> 4) * 8;   // K sub-chunk for fragments
    const int rr = lane & 15;         // row/col within fragment

    for (int kt = 0; kt < D / BK; ++kt) {
        const int k0 = kt * BK;
        #pragma unroll
        for (int r = 0; r < 2; ++r) {
            const int flat = r * 256 + wv * 64 + lane;   // 16B-unit index [0,512)
            const int row = flat >> 2;
            const int kk = (flat & 3) * 8;
            llds16(A + (size_t)(tileM + row) * D + k0 + kk,
                   As + (size_t)(r * 256 + wv * 64) * 8);
            llds16(Bt + (size_t)(tileN + row) * D + k0 + kk,
                   Bs + (size_t)(r * 256 + wv * 64) * 8);
        }
        __syncthreads();

        short8 af[4], bfr[4];
        #pragma unroll
        for (int mi = 0; mi < 4; ++mi)
            af[mi] = *(const short8*)&As[(wm * 64 + mi * 16 + rr) * BK + kg];
        #pragma unroll
        for (int ni = 0; ni < 4; ++ni)
            bfr[ni] = *(const short8*)&Bs[(wn * 64 + ni * 16 + rr) * BK + kg];
        #pragma unroll
        for (int mi = 0; mi < 4; ++mi)
            #pragma unroll
            for (int ni = 0; ni < 4; ++ni)
                acc[mi][ni] = __builtin_amdgcn_mfma_f32_16x16x32_bf16(af[mi], bfr[ni], acc[mi][ni], 0, 0, 0);
        __syncthreads();
    }

    // epilogue: bias + leaky relu, write bf16
    const int rgrp = lane >> 4;
    const int cidx = lane & 15;
    #pragma unroll
    for (int ni = 0; ni < 4; ++ni) {
        const int col = tileN + wn * 64 + ni * 16 + cidx;
        const float bv = bias[col];
        #pragma unroll
        for (int mi = 0; mi < 4; ++mi) {
            const int row0 = tileM + wm * 64 + mi * 16 + rgrp * 4;
            #pragma unroll
            for (int r2 = 0; r2 < 4; ++r2) {
                float v = acc[mi][ni][r2] + bv;
                v = v >= 0.f ? v : 0.01f * v;
                C[(size_t)(row0 + r2) * D + col] = f2bf(v);
            }
        }
    }
}

// ---------------- agg + LayerNorm (one block per batch) ----------------
__global__ __launch_bounds__(256)
void agg_ln_kernel(const unsigned short* __restrict__ s_next, const float* __restrict__ dist,
                   const float* __restrict__ q_in, float* __restrict__ q_out,
                   const float* __restrict__ gamma, const float* __restrict__ beta,
                   float* __restrict__ q_out2) {
    const int b = blockIdx.x, t = threadIdx.x, lane = t & 63, wv = t >> 6;
    __shared__ float dw[SEQ];
    __shared__ float red[8];
    __shared__ float mu_s, rstd_s;

    dw[t] = dist[b * SEQ + t];
    dw[t + 256] = dist[b * SEQ + 256 + t];
    __syncthreads();

    const unsigned short* base = s_next + (size_t)b * (SEQ * D) + 2 * t;
    float a0 = 0.f, a1 = 0.f;
    #pragma unroll 4
    for (int s = 0; s < SEQ; ++s) {
        unsigned int v = *(const unsigned int*)(base + (size_t)s * D);
        float w = dw[s];
        a0 += w * bf2f((unsigned short)(v & 0xffffu));
        a1 += w * bf2f((unsigned short)(v >> 16));
    }

    const int c0 = 2 * t;
    float x0 = q_in[b * D + c0] + a0;
    float x1 = q_in[b * D + c0 + 1] + a1;

    float sm = wred_sum(x0 + x1);
    if (lane == 0) red[wv] = sm;
    __syncthreads();
    if (t == 0) mu_s = (red[0] + red[1] + red[2] + red[3]) * (1.f / 512.f);
    __syncthreads();
    const float mu = mu_s;
    float d0 = x0 - mu, d1 = x1 - mu;
    float vv = wred_sum(d0 * d0 + d1 * d1);
    if (lane == 0) red[wv] = vv;
    __syncthreads();
    if (t == 0) rstd_s = rsqrtf((red[0] + red[1] + red[2] + red[3]) * (1.f / 512.f) + 1e-5f);
    __syncthreads();
    const float rs = rstd_s;
    float y0 = d0 * rs * gamma[c0] + beta[c0];
    float y1 = d1 * rs * gamma[c0 + 1] + beta[c0 + 1];
    q_out[b * D + c0] = y0;
    q_out[b * D + c0 + 1] = y1;
    if (q_out2) {
        q_out2[b * D + c0] = y0;
        q_out2[b * D + c0 + 1] = y1;
    }
}

// ---------------- W f32 -> bf16 ----------------
__global__ __launch_bounds__(256)
void convw_kernel(const float* __restrict__ W, unsigned short* __restrict__ Wb, int n4) {
    int i = blockIdx.x * 256 + threadIdx.x;
    if (i < n4) {
        float4 v = *(const float4*)(W + (size_t)i * 4);
        ushort4 o;
        o.x = f2bf(v.x); o.y = f2bf(v.y); o.z = f2bf(v.z); o.w = f2bf(v.w);
        *(ushort4*)(Wb + (size_t)i * 4) = o;
    }
}

extern "C" void kernel_launch(void* const* d_in, const int* in_sizes, int n_in,
                              void* d_out, int out_size, void* d_ws, size_t ws_size,
                              hipStream_t stream) {
    const float* query = (const float*)d_in[0];
    const float* state = (const float*)d_in[1];
    const float* W     = (const float*)d_in[2];
    const float* bias  = (const float*)d_in[3];
    const float* gamma = (const float*)d_in[4];
    const float* beta  = (const float*)d_in[5];

    float* out_q    = (float*)d_out;
    float* out_dist = (float*)d_out + BATCH * SEQ;

    char* ws = (char*)d_ws;
    const size_t SBYTES = (size_t)BATCH * SEQ * D * 2;   // 134,217,728
    unsigned short* sA = (unsigned short*)ws;
    unsigned short* sB = (unsigned short*)(ws + SBYTES);
    float* dist = (float*)(ws + 2 * SBYTES);
    float* qbuf = (float*)(ws + 2 * SBYTES + 524288);
    unsigned short* Wb = (unsigned short*)(ws + 2 * SBYTES + 1048576);

    hipMemcpyAsync(qbuf, query, (size_t)BATCH * D * sizeof(float),
                   hipMemcpyDeviceToDevice, stream);
    convw_kernel<<<768, 256, 0, stream>>>(W, Wb, 3 * D * D / 4);

    dim3 gemm_grid(BATCH * SEQ / BM, D / BN);

    // hop 0
    dist_kernel<true><<<BATCH, 256, 0, stream>>>(state, qbuf, dist, sA);
    gemm_kernel<<<gemm_grid, 256, 0, stream>>>(sA, Wb, bias, sB);
    agg_ln_kernel<<<BATCH, 256, 0, stream>>>(sB, dist, qbuf, qbuf, gamma, beta, nullptr);
    // hop 1
    dist_kernel<false><<<BATCH, 256, 0, stream>>>(sB, qbuf, dist, nullptr);
    gemm_kernel<<<gemm_grid, 256, 0, stream>>>(sB, Wb + D * D, bias + D, sA);
    agg_ln_kernel<<<BATCH, 256, 0, stream>>>(sA, dist, qbuf, qbuf, gamma, beta, nullptr);
    // hop 2
    dist_kernel<false><<<BATCH, 256, 0, stream>>>(sA, qbuf, dist, nullptr);
    gemm_kernel<<<gemm_grid, 256, 0, stream>>>(sA, Wb + 2 * D * D, bias + 2 * D, sB);
    agg_ln_kernel<<<BATCH, 256, 0, stream>>>(sB, dist, qbuf, qbuf, gamma, beta, out_q);
    // final dist -> output
    dist_kernel<false><<<BATCH, 256, 0, stream>>>(sB, qbuf, out_dist, nullptr);
}

// Round 2
// 627.289 us; speedup vs baseline: 1.5402x; 1.5402x over previous
//
#include <hip/hip_runtime.h>
#include <hip/hip_bf16.h>
#include <stdint.h>

#define D 512
#define BATCH 256
#define SEQ 512
// M = BATCH*SEQ = 131072

typedef __attribute__((ext_vector_type(8))) short short8;
typedef __attribute__((ext_vector_type(4))) float floatx4;

__device__ __forceinline__ float bf2f(unsigned short u) {
    union { unsigned int i; float f; } x; x.i = ((unsigned int)u) << 16; return x.f;
}
__device__ __forceinline__ unsigned short f2bf(float f) {
    union { float f; unsigned int i; } x; x.f = f;
    unsigned int i = x.i;
    unsigned int lsb = (i >> 16) & 1u;
    i += 0x7fffu + lsb;
    return (unsigned short)(i >> 16);
}

__device__ __forceinline__ float wred_sum(float v) {
    #pragma unroll
    for (int o = 32; o; o >>= 1) v += __shfl_xor(v, o, 64);
    return v;
}

__device__ __forceinline__ void llds16(const void* g, void* l) {
    auto gp = (const __attribute__((address_space(1))) void*)(g);
    auto lp = (__attribute__((address_space(3))) void*)(uintptr_t)(l);
    __builtin_amdgcn_global_load_lds(gp, lp, 16, 0, 0);
}

// ---------------- scores: raw 10*cos(q, s_row) per row, grid (4, B) ----------------
// F32IN: read f32 state_emb and write bf16 copy to s_bf_out.
template<bool F32IN>
__global__ __launch_bounds__(256)
void scores_kernel(const void* __restrict__ s_in_, const float* __restrict__ q,
                   float* __restrict__ scores, unsigned short* __restrict__ s_bf_out) {
    const int b = blockIdx.y;
    const int chunk = blockIdx.x;
    const int t = threadIdx.x, lane = t & 63, wv = t >> 6;

    float qv[8];
    {
        const float4* qp = (const float4*)(q + (size_t)b * D + lane * 8);
        float4 a = qp[0], c = qp[1];
        qv[0] = a.x; qv[1] = a.y; qv[2] = a.z; qv[3] = a.w;
        qv[4] = c.x; qv[5] = c.y; qv[6] = c.z; qv[7] = c.w;
    }
    float qn2 = 0.f;
    #pragma unroll
    for (int j = 0; j < 8; ++j) qn2 += qv[j] * qv[j];
    qn2 = wred_sum(qn2);
    const float qn = sqrtf(qn2);

    const int s0 = chunk * 128 + wv * 32;
    const size_t bbase = (size_t)b * (SEQ * D);
    for (int i = 0; i < 32; ++i) {
        const int s = s0 + i;
        const size_t off = bbase + (size_t)s * D + lane * 8;
        float v[8];
        if (F32IN) {
            const float4* p = (const float4*)((const float*)s_in_ + off);
            float4 a = p[0], c = p[1];
            v[0] = a.x; v[1] = a.y; v[2] = a.z; v[3] = a.w;
            v[4] = c.x; v[5] = c.y; v[6] = c.z; v[7] = c.w;
            short8 w;
            #pragma unroll
            for (int j = 0; j < 8; ++j) w[j] = (short)f2bf(v[j]);
            *(short8*)(s_bf_out + off) = w;
        } else {
            short8 w = *(const short8*)((const unsigned short*)s_in_ + off);
            #pragma unroll
            for (int j = 0; j < 8; ++j) v[j] = bf2f((unsigned short)w[j]);
        }
        float dot = 0.f, nr = 0.f;
        #pragma unroll
        for (int j = 0; j < 8; ++j) {
            dot += v[j] * qv[j];
            nr += v[j] * v[j];
        }
        dot = wred_sum(dot);
        nr  = wred_sum(nr);
        if (lane == 0) {
            scores[b * SEQ + s] = 10.f * dot / fmaxf(qn * sqrtf(nr), 1e-8f);
        }
    }
}

// ---------------- softmax over scores[b][0..511] ----------------
__global__ __launch_bounds__(256)
void softmax_kernel(const float* __restrict__ scores, float* __restrict__ dist_out) {
    const int b = blockIdx.x, t = threadIdx.x, lane = t & 63, wv = t >> 6;
    __shared__ float redbuf[8];
    __shared__ float m_s, sum_s;

    float s0 = scores[b * SEQ + t], s1 = scores[b * SEQ + 256 + t];
    float m = fmaxf(s0, s1);
    #pragma unroll
    for (int o = 32; o; o >>= 1) m = fmaxf(m, __shfl_xor(m, o, 64));
    if (lane == 0) redbuf[wv] = m;
    __syncthreads();
    if (t == 0) m_s = fmaxf(fmaxf(redbuf[0], redbuf[1]), fmaxf(redbuf[2], redbuf[3]));
    __syncthreads();
    const float mm = m_s;
    float e0 = __expf(s0 - mm), e1 = __expf(s1 - mm);
    float es = wred_sum(e0 + e1);
    if (lane == 0) redbuf[wv] = es;
    __syncthreads();
    if (t == 0) sum_s = redbuf[0] + redbuf[1] + redbuf[2] + redbuf[3];
    __syncthreads();
    const float inv = 1.f / sum_s;
    dist_out[b * SEQ + t] = e0 * inv;
    dist_out[b * SEQ + 256 + t] = e1 * inv;
}

// ---------------- GEMM: C = lrelu(A @ W^T + bias) + fused agg partials ----------------
// A: [M, K=512] bf16 row-major.  Bt = W: [N=512, K=512] bf16 row-major.
// part[slot][b*D + col], slot = (blockIdx.x & 3)*2 + wm  (8 slots), no atomics.
#define BM 128
#define BN 128
#define BK 32

__global__ __launch_bounds__(256)
void gemm_kernel(const unsigned short* __restrict__ A, const unsigned short* __restrict__ Bt,
                 const float* __restrict__ bias, const float* __restrict__ dist,
                 unsigned short* __restrict__ C, float* __restrict__ part) {
    __shared__ __align__(16) unsigned short As[BM * BK];
    __shared__ __align__(16) unsigned short Bs[BN * BK];
    __shared__ float dls[BM];

    const int tileM = blockIdx.x * BM;
    const int tileN = blockIdx.y * BN;
    const int t = threadIdx.x, lane = t & 63, wv = t >> 6;
    const int wm = wv >> 1, wn = wv & 1;

    if (t < BM) dls[t] = dist[tileM + t];

    floatx4 acc[4][4];
    #pragma unroll
    for (int i = 0; i < 4; ++i)
        #pragma unroll
        for (int j = 0; j < 4; ++j) acc[i][j] = {0.f, 0.f, 0.f, 0.f};

    const int kg = (lane >> 4) * 8;
    const int rr = lane & 15;

    for (int kt = 0; kt < D / BK; ++kt) {
        const int k0 = kt * BK;
        #pragma unroll
        for (int r = 0; r < 2; ++r) {
            const int flat = r * 256 + wv * 64 + lane;
            const int row = flat >> 2;
            const int kk = (flat & 3) * 8;
            llds16(A + (size_t)(tileM + row) * D + k0 + kk,
                   As + (size_t)(r * 256 + wv * 64) * 8);
            llds16(Bt + (size_t)(tileN + row) * D + k0 + kk,
                   Bs + (size_t)(r * 256 + wv * 64) * 8);
        }
        __syncthreads();

        short8 af[4], bfr[4];
        #pragma unroll
        for (int mi = 0; mi < 4; ++mi)
            af[mi] = *(const short8*)&As[(wm * 64 + mi * 16 + rr) * BK + kg];
        #pragma unroll
        for (int ni = 0; ni < 4; ++ni)
            bfr[ni] = *(const short8*)&Bs[(wn * 64 + ni * 16 + rr) * BK + kg];
        #pragma unroll
        for (int mi = 0; mi < 4; ++mi)
            #pragma unroll
            for (int ni = 0; ni < 4; ++ni)
                acc[mi][ni] = __builtin_amdgcn_mfma_f32_16x16x32_bf16(af[mi], bfr[ni], acc[mi][ni], 0, 0, 0);
        __syncthreads();
    }

    // epilogue: bias + leaky relu, bf16 C write, fused per-column agg partial
    const int rgrp = lane >> 4;
    const int cidx = lane & 15;
    const int b = tileM >> 9;
    const int slot = ((blockIdx.x & 3) << 1) + wm;
    #pragma unroll
    for (int ni = 0; ni < 4; ++ni) {
        const int col = tileN + wn * 64 + ni * 16 + cidx;
        const float bv = bias[col];
        float p = 0.f;
        #pragma unroll
        for (int mi = 0; mi < 4; ++mi) {
            const int rl0 = wm * 64 + mi * 16 + rgrp * 4;   // local row base
            #pragma unroll
            for (int r2 = 0; r2 < 4; ++r2) {
                float v = acc[mi][ni][r2] + bv;
                v = v >= 0.f ? v : 0.01f * v;
                C[(size_t)(tileM + rl0 + r2) * D + col] = f2bf(v);
                p += dls[rl0 + r2] * v;
            }
        }
        p += __shfl_xor(p, 16, 64);
        p += __shfl_xor(p, 32, 64);
        if (lane < 16) {
            part[(size_t)slot * (BATCH * D) + (size_t)b * D + col] = p;
        }
    }
}

// ---------------- agg partial reduce + residual + LayerNorm ----------------
__global__ __launch_bounds__(256)
void aggln_kernel(const float* __restrict__ part, const float* __restrict__ q_in,
                  const float* __restrict__ gamma, const float* __restrict__ beta,
                  float* __restrict__ q_out) {
    const int b = blockIdx.x, t = threadIdx.x, lane = t & 63, wv = t >> 6;
    __shared__ float red[8];
    __shared__ float mu_s, rstd_s;

    const int c0 = 2 * t;
    float a0 = 0.f, a1 = 0.f;
    #pragma unroll
    for (int slot = 0; slot < 8; ++slot) {
        float2 v = *(const float2*)(part + (size_t)slot * (BATCH * D) + (size_t)b * D + c0);
        a0 += v.x; a1 += v.y;
    }
    float x0 = q_in[b * D + c0] + a0;
    float x1 = q_in[b * D + c0 + 1] + a1;

    float sm = wred_sum(x0 + x1);
    if (lane == 0) red[wv] = sm;
    __syncthreads();
    if (t == 0) mu_s = (red[0] + red[1] + red[2] + red[3]) * (1.f / 512.f);
    __syncthreads();
    const float mu = mu_s;
    float d0 = x0 - mu, d1 = x1 - mu;
    float vv = wred_sum(d0 * d0 + d1 * d1);
    if (lane == 0) red[wv] = vv;
    __syncthreads();
    if (t == 0) rstd_s = rsqrtf((red[0] + red[1] + red[2] + red[3]) * (1.f / 512.f) + 1e-5f);
    __syncthreads();
    const float rs = rstd_s;
    q_out[b * D + c0]     = d0 * rs * gamma[c0]     + beta[c0];
    q_out[b * D + c0 + 1] = d1 * rs * gamma[c0 + 1] + beta[c0 + 1];
}

// ---------------- W f32 -> bf16 ----------------
__global__ __launch_bounds__(256)
void convw_kernel(const float* __restrict__ W, unsigned short* __restrict__ Wb, int n4) {
    int i = blockIdx.x * 256 + threadIdx.x;
    if (i < n4) {
        float4 v = *(const float4*)(W + (size_t)i * 4);
        ushort4 o;
        o.x = f2bf(v.x); o.y = f2bf(v.y); o.z = f2bf(v.z); o.w = f2bf(v.w);
        *(ushort4*)(Wb + (size_t)i * 4) = o;
    }
}

extern "C" void kernel_launch(void* const* d_in, const int* in_sizes, int n_in,
                              void* d_out, int out_size, void* d_ws, size_t ws_size,
                              hipStream_t stream) {
    const float* query = (const float*)d_in[0];
    const float* state = (const float*)d_in[1];
    const float* W     = (const float*)d_in[2];
    const float* bias  = (const float*)d_in[3];
    const float* gamma = (const float*)d_in[4];
    const float* beta  = (const float*)d_in[5];

    float* out_q    = (float*)d_out;
    float* out_dist = (float*)d_out + BATCH * SEQ;

    char* ws = (char*)d_ws;
    const size_t SBYTES = (size_t)BATCH * SEQ * D * 2;   // 134,217,728
    unsigned short* sA = (unsigned short*)ws;
    unsigned short* sB = (unsigned short*)(ws + SBYTES);
    char* ext = ws + 2 * SBYTES;
    float* scores = (float*)ext;                      // 512 KB
    float* dist   = (float*)(ext + 524288);           // 512 KB
    float* qbuf   = (float*)(ext + 2 * 524288);       // 512 KB
    float* part   = (float*)(ext + 3 * 524288);       // 8 * 512 KB = 4 MB
    unsigned short* Wb = (unsigned short*)(ext + 11 * 524288);  // 1.5 MB

    hipMemcpyAsync(qbuf, query, (size_t)BATCH * D * sizeof(float),
                   hipMemcpyDeviceToDevice, stream);
    convw_kernel<<<768, 256, 0, stream>>>(W, Wb, 3 * D * D / 4);

    dim3 sgrid(4, BATCH);
    dim3 gemm_grid(BATCH * SEQ / BM, D / BN);

    // hop 0
    scores_kernel<true><<<sgrid, 256, 0, stream>>>(state, qbuf, scores, sA);
    softmax_kernel<<<BATCH, 256, 0, stream>>>(scores, dist);
    gemm_kernel<<<gemm_grid, 256, 0, stream>>>(sA, Wb, bias, dist, sB, part);
    aggln_kernel<<<BATCH, 256, 0, stream>>>(part, qbuf, gamma, beta, qbuf);
    // hop 1
    scores_kernel<false><<<sgrid, 256, 0, stream>>>(sB, qbuf, scores, nullptr);
    softmax_kernel<<<BATCH, 256, 0, stream>>>(scores, dist);
    gemm_kernel<<<gemm_grid, 256, 0, stream>>>(sB, Wb + D * D, bias + D, dist, sA, part);
    aggln_kernel<<<BATCH, 256, 0, stream>>>(part, qbuf, gamma, beta, qbuf);
    // hop 2
    scores_kernel<false><<<sgrid, 256, 0, stream>>>(sA, qbuf, scores, nullptr);
    softmax_kernel<<<BATCH, 256, 0, stream>>>(scores, dist);
    gemm_kernel<<<gemm_grid, 256, 0, stream>>>(sA, Wb + 2 * D * D, bias + 2 * D, dist, sB, part);
    aggln_kernel<<<BATCH, 256, 0, stream>>>(part, qbuf, gamma, beta, out_q);
    // final dist
    scores_kernel<false><<<sgrid, 256, 0, stream>>>(sB, out_q, scores, nullptr);
    softmax_kernel<<<BATCH, 256, 0, stream>>>(scores, out_dist);
}

// Round 3
// 561.061 us; speedup vs baseline: 1.7220x; 1.1180x over previous
//
#include <hip/hip_runtime.h>
#include <hip/hip_bf16.h>
#include <stdint.h>

#define D 512
#define BATCH 256
#define SEQ 512
// M = BATCH*SEQ = 131072

typedef __attribute__((ext_vector_type(8))) short short8;
typedef __attribute__((ext_vector_type(4))) float floatx4;

__device__ __forceinline__ float bf2f(unsigned short u) {
    union { unsigned int i; float f; } x; x.i = ((unsigned int)u) << 16; return x.f;
}
__device__ __forceinline__ unsigned short f2bf(float f) {
    union { float f; unsigned int i; } x; x.f = f;
    unsigned int i = x.i;
    unsigned int lsb = (i >> 16) & 1u;
    i += 0x7fffu + lsb;
    return (unsigned short)(i >> 16);
}

__device__ __forceinline__ float wred_sum(float v) {
    #pragma unroll
    for (int o = 32; o; o >>= 1) v += __shfl_xor(v, o, 64);
    return v;
}

__device__ __forceinline__ void llds16(const void* g, void* l) {
    auto gp = (const __attribute__((address_space(1))) void*)(g);
    auto lp = (__attribute__((address_space(3))) void*)(uintptr_t)(l);
    __builtin_amdgcn_global_load_lds(gp, lp, 16, 0, 0);
}

// ---------------- scores: raw 10*cos(q, s_row) per row, grid (4, B) ----------------
template<bool F32IN>
__global__ __launch_bounds__(256)
void scores_kernel(const void* __restrict__ s_in_, const float* __restrict__ q,
                   float* __restrict__ scores, unsigned short* __restrict__ s_bf_out) {
    const int b = blockIdx.y;
    const int chunk = blockIdx.x;
    const int t = threadIdx.x, lane = t & 63, wv = t >> 6;

    float qv[8];
    {
        const float4* qp = (const float4*)(q + (size_t)b * D + lane * 8);
        float4 a = qp[0], c = qp[1];
        qv[0] = a.x; qv[1] = a.y; qv[2] = a.z; qv[3] = a.w;
        qv[4] = c.x; qv[5] = c.y; qv[6] = c.z; qv[7] = c.w;
    }
    float qn2 = 0.f;
    #pragma unroll
    for (int j = 0; j < 8; ++j) qn2 += qv[j] * qv[j];
    qn2 = wred_sum(qn2);
    const float qn = sqrtf(qn2);

    const int s0 = chunk * 128 + wv * 32;
    const size_t bbase = (size_t)b * (SEQ * D);
    for (int i = 0; i < 32; ++i) {
        const int s = s0 + i;
        const size_t off = bbase + (size_t)s * D + lane * 8;
        float v[8];
        if (F32IN) {
            const float4* p = (const float4*)((const float*)s_in_ + off);
            float4 a = p[0], c = p[1];
            v[0] = a.x; v[1] = a.y; v[2] = a.z; v[3] = a.w;
            v[4] = c.x; v[5] = c.y; v[6] = c.z; v[7] = c.w;
            short8 w;
            #pragma unroll
            for (int j = 0; j < 8; ++j) w[j] = (short)f2bf(v[j]);
            *(short8*)(s_bf_out + off) = w;
        } else {
            short8 w = *(const short8*)((const unsigned short*)s_in_ + off);
            #pragma unroll
            for (int j = 0; j < 8; ++j) v[j] = bf2f((unsigned short)w[j]);
        }
        float dot = 0.f, nr = 0.f;
        #pragma unroll
        for (int j = 0; j < 8; ++j) {
            dot += v[j] * qv[j];
            nr += v[j] * v[j];
        }
        dot = wred_sum(dot);
        nr  = wred_sum(nr);
        if (lane == 0) {
            scores[b * SEQ + s] = 10.f * dot / fmaxf(qn * sqrtf(nr), 1e-8f);
        }
    }
}

// ---------------- softmax over scores[b][0..511] ----------------
__global__ __launch_bounds__(256)
void softmax_kernel(const float* __restrict__ scores, float* __restrict__ dist_out) {
    const int b = blockIdx.x, t = threadIdx.x, lane = t & 63, wv = t >> 6;
    __shared__ float redbuf[8];
    __shared__ float m_s, sum_s;

    float s0 = scores[b * SEQ + t], s1 = scores[b * SEQ + 256 + t];
    float m = fmaxf(s0, s1);
    #pragma unroll
    for (int o = 32; o; o >>= 1) m = fmaxf(m, __shfl_xor(m, o, 64));
    if (lane == 0) redbuf[wv] = m;
    __syncthreads();
    if (t == 0) m_s = fmaxf(fmaxf(redbuf[0], redbuf[1]), fmaxf(redbuf[2], redbuf[3]));
    __syncthreads();
    const float mm = m_s;
    float e0 = __expf(s0 - mm), e1 = __expf(s1 - mm);
    float es = wred_sum(e0 + e1);
    if (lane == 0) redbuf[wv] = es;
    __syncthreads();
    if (t == 0) sum_s = redbuf[0] + redbuf[1] + redbuf[2] + redbuf[3];
    __syncthreads();
    const float inv = 1.f / sum_s;
    dist_out[b * SEQ + t] = e0 * inv;
    dist_out[b * SEQ + 256 + t] = e1 * inv;
}

// ---------------- GEMM: C = lrelu(A @ W^T + bias) + fused agg partials ----------------
// A: [M, K=512] bf16 row-major.  Bt = W: [N=512, K=512] bf16 row-major.
// grid = (N/BN = 4, M/BM = 1024)  -> blocks sharing an A-tile are dispatch-adjacent.
// 2-phase double-buffered pipeline (T3 minimal) + XOR-swizzled LDS (T2, rule#21:
// linear LDS dest, inverse-swizzled global source, swizzled ds_read).
#define BM 128
#define BN 128
#define BK 64
#define NKT (D / BK)

__global__ __launch_bounds__(256)
void gemm_kernel(const unsigned short* __restrict__ A, const unsigned short* __restrict__ Bt,
                 const float* __restrict__ bias, const float* __restrict__ dist,
                 unsigned short* __restrict__ C, float* __restrict__ part) {
    __shared__ __align__(16) unsigned short As[2][BM * BK];
    __shared__ __align__(16) unsigned short Bs[2][BN * BK];
    __shared__ float dls[BM];

    const int tileN = blockIdx.x * BN;
    const int tileM = blockIdx.y * BM;
    const int t = threadIdx.x, lane = t & 63, wv = t >> 6;
    const int wm = wv >> 1, wn = wv & 1;

    if (t < BM) dls[t] = dist[tileM + t];

    // Staging: LDS chunk (r, c) holds global k-chunk (c ^ (r&7)).  Dest is
    // linear (wave-uniform base + lane*16); source address carries the swizzle.
    const unsigned short* gsrcA[4];
    const unsigned short* gsrcB[4];
    int ldst[4];
    #pragma unroll
    for (int i = 0; i < 4; ++i) {
        const int f = i * 256 + t;          // 16B-chunk index in [0,1024)
        const int r = f >> 3, c = f & 7;
        const int gc = c ^ (r & 7);
        gsrcA[i] = A + (size_t)(tileM + r) * D + gc * 8;
        gsrcB[i] = Bt + (size_t)(tileN + r) * D + gc * 8;
        ldst[i] = f * 8;                    // shorts
    }

    floatx4 acc[4][4];
    #pragma unroll
    for (int i = 0; i < 4; ++i)
        #pragma unroll
        for (int j = 0; j < 4; ++j) acc[i][j] = {0.f, 0.f, 0.f, 0.f};

    const int rr = lane & 15, lg = lane >> 4, x7 = rr & 7;

    // prologue: stage k-tile 0 into buffer 0
    #pragma unroll
    for (int i = 0; i < 4; ++i) {
        llds16(gsrcA[i], &As[0][ldst[i]]);
        llds16(gsrcB[i], &Bs[0][ldst[i]]);
    }
    __syncthreads();

    for (int kt = 0; kt < NKT; ++kt) {
        const int cur = kt & 1;
        if (kt + 1 < NKT) {
            const int ko = (kt + 1) * BK;
            #pragma unroll
            for (int i = 0; i < 4; ++i) {
                llds16(gsrcA[i] + ko, &As[cur ^ 1][ldst[i]]);
                llds16(gsrcB[i] + ko, &Bs[cur ^ 1][ldst[i]]);
            }
        }

        short8 af[4][2], bf8[4][2];
        #pragma unroll
        for (int mi = 0; mi < 4; ++mi) {
            const int rl = wm * 64 + mi * 16 + rr;
            #pragma unroll
            for (int h = 0; h < 2; ++h)
                af[mi][h] = *(const short8*)&As[cur][rl * 64 + (((h << 2) | lg) ^ x7) * 8];
        }
        #pragma unroll
        for (int ni = 0; ni < 4; ++ni) {
            const int rl = wn * 64 + ni * 16 + rr;
            #pragma unroll
            for (int h = 0; h < 2; ++h)
                bf8[ni][h] = *(const short8*)&Bs[cur][rl * 64 + (((h << 2) | lg) ^ x7) * 8];
        }
        #pragma unroll
        for (int h = 0; h < 2; ++h)
            #pragma unroll
            for (int mi = 0; mi < 4; ++mi)
                #pragma unroll
                for (int ni = 0; ni < 4; ++ni)
                    acc[mi][ni] = __builtin_amdgcn_mfma_f32_16x16x32_bf16(af[mi][h], bf8[ni][h], acc[mi][ni], 0, 0, 0);
        __syncthreads();   // drains vmcnt (next-tile stage) + lgkmcnt; one barrier per K-step
    }

    // epilogue: bias + leaky relu, bf16 C write, fused per-column agg partial
    const int rgrp = lane >> 4;
    const int cidx = lane & 15;
    const int b = tileM >> 9;
    const int slot = ((blockIdx.y & 3) << 1) + wm;
    #pragma unroll
    for (int ni = 0; ni < 4; ++ni) {
        const int col = tileN + wn * 64 + ni * 16 + cidx;
        const float bv = bias[col];
        float p = 0.f;
        #pragma unroll
        for (int mi = 0; mi < 4; ++mi) {
            const int rl0 = wm * 64 + mi * 16 + rgrp * 4;
            #pragma unroll
            for (int r2 = 0; r2 < 4; ++r2) {
                float v = acc[mi][ni][r2] + bv;
                v = v >= 0.f ? v : 0.01f * v;
                C[(size_t)(tileM + rl0 + r2) * D + col] = f2bf(v);
                p += dls[rl0 + r2] * v;
            }
        }
        p += __shfl_xor(p, 16, 64);
        p += __shfl_xor(p, 32, 64);
        if (lane < 16) {
            part[(size_t)slot * (BATCH * D) + (size_t)b * D + col] = p;
        }
    }
}

// ---------------- agg partial reduce + residual + LayerNorm ----------------
__global__ __launch_bounds__(256)
void aggln_kernel(const float* __restrict__ part, const float* __restrict__ q_in,
                  const float* __restrict__ gamma, const float* __restrict__ beta,
                  float* __restrict__ q_out) {
    const int b = blockIdx.x, t = threadIdx.x, lane = t & 63, wv = t >> 6;
    __shared__ float red[8];
    __shared__ float mu_s, rstd_s;

    const int c0 = 2 * t;
    float a0 = 0.f, a1 = 0.f;
    #pragma unroll
    for (int slot = 0; slot < 8; ++slot) {
        float2 v = *(const float2*)(part + (size_t)slot * (BATCH * D) + (size_t)b * D + c0);
        a0 += v.x; a1 += v.y;
    }
    float x0 = q_in[b * D + c0] + a0;
    float x1 = q_in[b * D + c0 + 1] + a1;

    float sm = wred_sum(x0 + x1);
    if (lane == 0) red[wv] = sm;
    __syncthreads();
    if (t == 0) mu_s = (red[0] + red[1] + red[2] + red[3]) * (1.f / 512.f);
    __syncthreads();
    const float mu = mu_s;
    float d0 = x0 - mu, d1 = x1 - mu;
    float vv = wred_sum(d0 * d0 + d1 * d1);
    if (lane == 0) red[wv] = vv;
    __syncthreads();
    if (t == 0) rstd_s = rsqrtf((red[0] + red[1] + red[2] + red[3]) * (1.f / 512.f) + 1e-5f);
    __syncthreads();
    const float rs = rstd_s;
    q_out[b * D + c0]     = d0 * rs * gamma[c0]     + beta[c0];
    q_out[b * D + c0 + 1] = d1 * rs * gamma[c0 + 1] + beta[c0 + 1];
}

// ---------------- W f32 -> bf16 ----------------
__global__ __launch_bounds__(256)
void convw_kernel(const float* __restrict__ W, unsigned short* __restrict__ Wb, int n4) {
    int i = blockIdx.x * 256 + threadIdx.x;
    if (i < n4) {
        float4 v = *(const float4*)(W + (size_t)i * 4);
        ushort4 o;
        o.x = f2bf(v.x); o.y = f2bf(v.y); o.z = f2bf(v.z); o.w = f2bf(v.w);
        *(ushort4*)(Wb + (size_t)i * 4) = o;
    }
}

extern "C" void kernel_launch(void* const* d_in, const int* in_sizes, int n_in,
                              void* d_out, int out_size, void* d_ws, size_t ws_size,
                              hipStream_t stream) {
    const float* query = (const float*)d_in[0];
    const float* state = (const float*)d_in[1];
    const float* W     = (const float*)d_in[2];
    const float* bias  = (const float*)d_in[3];
    const float* gamma = (const float*)d_in[4];
    const float* beta  = (const float*)d_in[5];

    float* out_q    = (float*)d_out;
    float* out_dist = (float*)d_out + BATCH * SEQ;

    char* ws = (char*)d_ws;
    const size_t SBYTES = (size_t)BATCH * SEQ * D * 2;   // 134,217,728
    unsigned short* sA = (unsigned short*)ws;
    unsigned short* sB = (unsigned short*)(ws + SBYTES);
    char* ext = ws + 2 * SBYTES;
    float* scores = (float*)ext;                      // 512 KB
    float* dist   = (float*)(ext + 524288);           // 512 KB
    float* qbuf   = (float*)(ext + 2 * 524288);       // 512 KB
    float* part   = (float*)(ext + 3 * 524288);       // 8 * 512 KB = 4 MB
    unsigned short* Wb = (unsigned short*)(ext + 11 * 524288);  // 1.5 MB

    hipMemcpyAsync(qbuf, query, (size_t)BATCH * D * sizeof(float),
                   hipMemcpyDeviceToDevice, stream);
    convw_kernel<<<768, 256, 0, stream>>>(W, Wb, 3 * D * D / 4);

    dim3 sgrid(4, BATCH);
    dim3 gemm_grid(D / BN, BATCH * SEQ / BM);

    // hop 0
    scores_kernel<true><<<sgrid, 256, 0, stream>>>(state, qbuf, scores, sA);
    softmax_kernel<<<BATCH, 256, 0, stream>>>(scores, dist);
    gemm_kernel<<<gemm_grid, 256, 0, stream>>>(sA, Wb, bias, dist, sB, part);
    aggln_kernel<<<BATCH, 256, 0, stream>>>(part, qbuf, gamma, beta, qbuf);
    // hop 1
    scores_kernel<false><<<sgrid, 256, 0, stream>>>(sB, qbuf, scores, nullptr);
    softmax_kernel<<<BATCH, 256, 0, stream>>>(scores, dist);
    gemm_kernel<<<gemm_grid, 256, 0, stream>>>(sB, Wb + D * D, bias + D, dist, sA, part);
    aggln_kernel<<<BATCH, 256, 0, stream>>>(part, qbuf, gamma, beta, qbuf);
    // hop 2
    scores_kernel<false><<<sgrid, 256, 0, stream>>>(sA, qbuf, scores, nullptr);
    softmax_kernel<<<BATCH, 256, 0, stream>>>(scores, dist);
    gemm_kernel<<<gemm_grid, 256, 0, stream>>>(sA, Wb + 2 * D * D, bias + 2 * D, dist, sB, part);
    aggln_kernel<<<BATCH, 256, 0, stream>>>(part, qbuf, gamma, beta, out_q);
    // final dist
    scores_kernel<false><<<sgrid, 256, 0, stream>>>(sB, out_q, scores, nullptr);
    softmax_kernel<<<BATCH, 256, 0, stream>>>(scores, out_dist);
}